// Round 3
// baseline (808.915 us; speedup 1.0000x reference)
//
#include <hip/hip_runtime.h>
#include <hip/hip_bf16.h>
#include <hip/hip_cooperative_groups.h>

namespace cg = cooperative_groups;

#define NN 50000
#define EE 1600000
#define DD 512
#define HH 256
#define GG 16
#define BK 96     // bucket capacity (deg ~ Poisson(32), P(>=96) ~ 1e-18)
#define NCH 256   // edge chunks
#define CHSZ 6250 // EE / NCH

#define NBLD 768      // coop grid: 3 blocks/CU * 256 CU (LDS 50KB -> 3/CU co-resident)
#define NUNIT_X 6250  // x-convert ticket units (4096 floats each)
#define NUNIT_W 64    // weight-convert ticket units
#define NUNITS (NUNIT_X + NUNIT_W)

typedef long fp8x8;                                         // 8 fp8 bytes = 2 VGPRs
typedef __attribute__((ext_vector_type(4))) float f32x4;
typedef __attribute__((ext_vector_type(2))) float f32x2;

__device__ __forceinline__ unsigned char f2fp8(float f) {
    return (unsigned char)(__builtin_amdgcn_cvt_pk_fp8_f32(f, f, 0, false) & 0xff);
}
__device__ __forceinline__ unsigned int pk4fp8(float a, float b, float c, float d) {
    unsigned int r = __builtin_amdgcn_cvt_pk_fp8_f32(a, b, 0, false);
    return __builtin_amdgcn_cvt_pk_fp8_f32(c, d, r, true);
}

// ================= cooperative build: hist(u8x4) + converts | scan | place =================
// One launch replaces k_hist_cvt + k_scan + k_place. u8-packed per-chunk histograms halve
// hist traffic; hist and place read the edge list ONCE each (old: 4x / 8x dst re-reads).
// LDS 50000B -> 3 blocks/CU -> grid 768 co-resident (coop requirement).
__global__ __launch_bounds__(256) void k_build(const int* __restrict__ ei,
    unsigned int* __restrict__ histg,   // [NCH][12500] : 4 dsts per u32 (u8 counts)
    unsigned int* __restrict__ offg,    // [NCH][25000] : 2 dsts per u32 (u16 offsets)
    int* __restrict__ cnt, float* __restrict__ dinv,
    unsigned short* __restrict__ bucket,
    const float* __restrict__ x, unsigned char* __restrict__ xb,
    const float* __restrict__ W1, const float* __restrict__ W2, const float* __restrict__ W3,
    unsigned char* __restrict__ W1t, unsigned char* __restrict__ W2t, unsigned char* __restrict__ W3t,
    unsigned int* __restrict__ gticket)
{
    __shared__ unsigned int sh[12500];   // 50000 B: hist counters / scan partials / place cursors
    const int b = blockIdx.x, t = threadIdx.x;

    // ---------- phase A: per-chunk dst histogram (blocks < NCH), then ticketed converts ----------
    if (b < NCH) {
        for (int i = t; i < 12500; i += 256) sh[i] = 0u;
        __syncthreads();
        const int base = b * CHSZ;
        for (int k = 0; k < 25; ++k) {
            int o = k * 256 + t;
            if (o < CHSZ) {
                int d = ei[EE + base + o];
                atomicAdd(&sh[d >> 2], 1u << ((d & 3) * 8));
            }
        }
        __syncthreads();
        unsigned int* hrow = histg + (size_t)b * 12500;
        for (int i = t; i < 12500; i += 256) hrow[i] = sh[i];
    }
    // ticketed convert work (all blocks; hist blocks join when done)
    for (;;) {
        __syncthreads();
        if (t == 0) sh[0] = atomicAdd(gticket, 1u);
        __syncthreads();
        unsigned int u = sh[0];
        if (u >= NUNITS) break;
        if (u < NUNIT_X) {
            size_t i0 = ((size_t)u * 256 + t) * 16;       // 16 floats per thread
            float4 v0 = *(const float4*)(x + i0);
            float4 v1 = *(const float4*)(x + i0 + 4);
            float4 v2 = *(const float4*)(x + i0 + 8);
            float4 v3 = *(const float4*)(x + i0 + 12);
            uint4 o;
            o.x = pk4fp8(v0.x, v0.y, v0.z, v0.w);
            o.y = pk4fp8(v1.x, v1.y, v1.z, v1.w);
            o.z = pk4fp8(v2.x, v2.y, v2.z, v2.w);
            o.w = pk4fp8(v3.x, v3.y, v3.z, v3.w);
            *(uint4*)(xb + i0) = o;
        } else {
            int wu = u - NUNIT_X;
            #pragma unroll
            for (int c = 0; c < 16; ++c) {
                int e = wu * 4096 + c * 256 + t;
                if (e < 131072) {
                    int k = e >> 8, n = e & 255;
                    W1t[(size_t)n * 512 + k] = f2fp8(W1[e]);
                } else if (e < 196608) {
                    int q = e - 131072; int k = q >> 8, n = q & 255;
                    W2t[(size_t)n * 256 + k] = f2fp8(W2[q]);
                } else {
                    int q = e - 196608; int k = q >> 8, n = q & 255;
                    W3t[(size_t)n * 256 + k] = f2fp8(W3[q]);
                }
            }
        }
    }
    cg::this_grid().sync();

    // ---------- phase B: exclusive scan over chunks (u8 lanes, carry-free packed sums) ----------
    // 391 tasks; task = 32 dst4-groups. Thread (g = t>>5) owns 32 chunks of group g4.
    if (b < 391) {
        const int il = t & 31, g = t >> 5;
        const int g4 = b * 32 + il;
        const bool ok = (g4 < 12500);
        unsigned hv[32];
        unsigned s02 = 0, s13 = 0;        // byte0/2 and byte1/3 partial sums (u16 halves, no carry: <=255*32)
        if (ok) {
            const unsigned* hp = histg + (size_t)(g * 32) * 12500 + g4;
            #pragma unroll
            for (int jj = 0; jj < 32; ++jj) hv[jj] = hp[(size_t)jj * 12500];
            #pragma unroll
            for (int jj = 0; jj < 32; ++jj) { s02 += hv[jj] & 0x00ff00ffu; s13 += (hv[jj] >> 8) & 0x00ff00ffu; }
        }
        sh[t * 2] = s02; sh[t * 2 + 1] = s13;
        __syncthreads();
        unsigned b02 = 0, b13 = 0;
        #pragma unroll
        for (int g2 = 0; g2 < 7; ++g2)
            if (g2 < g) { b02 += sh[(g2 * 32 + il) * 2]; b13 += sh[(g2 * 32 + il) * 2 + 1]; }
        if (ok && g == 7) {
            unsigned t02 = b02 + s02, t13 = b13 + s13;
            int4 cv; cv.x = (int)(t02 & 0xffffu); cv.y = (int)(t13 & 0xffffu);
            cv.z = (int)(t02 >> 16);      cv.w = (int)(t13 >> 16);
            *(int4*)(cnt + 4 * g4) = cv;
            float4 dv;
            dv.x = rsqrtf((float)cv.x + 1.0f); dv.y = rsqrtf((float)cv.y + 1.0f);
            dv.z = rsqrtf((float)cv.z + 1.0f); dv.w = rsqrtf((float)cv.w + 1.0f);
            *(float4*)(dinv + 4 * g4) = dv;
        }
        if (ok) {
            unsigned r0 = b02 & 0xffffu, r2 = b02 >> 16, r1 = b13 & 0xffffu, r3 = b13 >> 16;
            #pragma unroll
            for (int jj = 0; jj < 32; ++jj) {
                uint2 wv; wv.x = r0 | (r1 << 16); wv.y = r2 | (r3 << 16);
                *(uint2*)(offg + (size_t)(g * 32 + jj) * 25000 + 2 * g4) = wv;
                unsigned h = hv[jj];
                r0 += h & 0xffu; r1 += (h >> 8) & 0xffu; r2 += (h >> 16) & 0xffu; r3 += h >> 24;
            }
        }
    }
    cg::this_grid().sync();

    // ---------- phase C: placement, one chunk per block, single edge read ----------
    if (b < NCH) {
        for (int i = t; i < 12500; i += 256) sh[i] = 0u;
        __syncthreads();
        const int base = b * CHSZ;
        for (int k = 0; k < 25; ++k) {
            int o = k * 256 + t;
            if (o < CHSZ) {
                int d = ei[EE + base + o];
                int s = ei[base + o];
                unsigned old = atomicAdd(&sh[d >> 2], 1u << ((d & 3) * 8));
                unsigned rank = (old >> ((d & 3) * 8)) & 0xffu;
                unsigned ov = offg[(size_t)b * 25000 + (d >> 1)];
                unsigned pos = ((d & 1) ? (ov >> 16) : (ov & 0xffffu)) + rank;
                if (pos < BK) bucket[(size_t)d * BK + pos] = (unsigned short)s;
            }
        }
    }
}

// ---------------- fp8 MFMA GEMM: C = fp8(dinv[row] * (A @ Bt^T)) ----------------
// A [M][K] fp8, Bt [256][K] fp8. Tile 128x128, BK=32 (32 B staging rows).
__global__ __launch_bounds__(256) void k_gemm_fp8(const unsigned char* __restrict__ A,
                                                  const unsigned char* __restrict__ Bt,
                                                  const float* __restrict__ dinv,
                                                  unsigned char* __restrict__ C, int M, int K) {
    __shared__ unsigned char As[128 * 32];
    __shared__ unsigned char Bs[128 * 32];
    const int tid  = threadIdx.x;
    const int wave = tid >> 6;
    const int lane = tid & 63;
    const int row0 = blockIdx.x * 128;
    const int col0 = blockIdx.y * 128;
    const int wr = wave & 1;
    const int wc = wave >> 1;
    const int l15 = lane & 15;
    const int quad = lane >> 4;

    const int sr = tid >> 1;          // 0..127
    const int sk = (tid & 1) * 16;    // byte offset in k

    int ar = row0 + sr; if (ar >= M) ar = M - 1;
    const int bc = col0 + sr;

    f32x4 acc[4][4];
    #pragma unroll
    for (int i = 0; i < 4; ++i)
        #pragma unroll
        for (int j = 0; j < 4; ++j)
            acc[i][j] = (f32x4){0.f, 0.f, 0.f, 0.f};

    for (int kb = 0; kb < K; kb += 32) {
        const unsigned char* ga = A + (size_t)ar * K + kb + sk;
        const unsigned char* gb = Bt + (size_t)bc * K + kb + sk;
        __builtin_amdgcn_global_load_lds((const __attribute__((address_space(1))) void*)ga,
            (__attribute__((address_space(3))) void*)&As[wave * 1024], 16, 0, 0);
        __builtin_amdgcn_global_load_lds((const __attribute__((address_space(1))) void*)gb,
            (__attribute__((address_space(3))) void*)&Bs[wave * 1024], 16, 0, 0);
        __syncthreads();

        fp8x8 af[4], bfr[4];
        #pragma unroll
        for (int mi = 0; mi < 4; ++mi)
            af[mi] = *(const fp8x8*)&As[(wr * 64 + mi * 16 + l15) * 32 + quad * 8];
        #pragma unroll
        for (int ni = 0; ni < 4; ++ni)
            bfr[ni] = *(const fp8x8*)&Bs[(wc * 64 + ni * 16 + l15) * 32 + quad * 8];
        #pragma unroll
        for (int mi = 0; mi < 4; ++mi)
            #pragma unroll
            for (int ni = 0; ni < 4; ++ni)
                acc[mi][ni] = __builtin_amdgcn_mfma_f32_16x16x32_fp8_fp8(af[mi], bfr[ni], acc[mi][ni], 0, 0, 0);
        __syncthreads();
    }

    #pragma unroll
    for (int mi = 0; mi < 4; ++mi) {
        #pragma unroll
        for (int r = 0; r < 4; ++r) {
            int grow = row0 + wr * 64 + mi * 16 + quad * 4 + r;
            if (grow < M) {
                float ds = dinv[grow];
                #pragma unroll
                for (int ni = 0; ni < 4; ++ni) {
                    int gcol = col0 + wc * 64 + ni * 16 + l15;
                    C[(size_t)grow * 256 + gcol] = f2fp8(ds * acc[mi][ni][r]);
                }
            }
        }
    }
}

// ---------------- aggregation over fp8 rows; fp8 h output ----------------
__global__ __launch_bounds__(256) void k_agg(const unsigned int* __restrict__ m,   // [NN][64] dwords
                                             const float* __restrict__ bias,
                                             const float* __restrict__ dinv, const int* __restrict__ cnt,
                                             const unsigned short* __restrict__ bucket,
                                             unsigned int* __restrict__ outb,      // [NN][64] dwords fp8
                                             int do_relu) {
    int lane = threadIdx.x & 63;
    int node = blockIdx.x * 4 + (threadIdx.x >> 6);
    if (node >= NN) return;
    const unsigned int* mrow = m + lane;
    unsigned int v = mrow[(size_t)node * 64];
    f32x2 lo = __builtin_amdgcn_cvt_pk_f32_fp8(v, false);
    f32x2 hi = __builtin_amdgcn_cvt_pk_f32_fp8(v, true);
    float4 acc = make_float4(lo.x, lo.y, hi.x, hi.y);
    int n = cnt[node]; if (n > BK) n = BK;
    const unsigned short* cs = bucket + (size_t)node * BK;
    int p = 0;
    for (; p + 8 <= n; p += 8) {
        int s0 = cs[p], s1 = cs[p + 1], s2 = cs[p + 2], s3 = cs[p + 3];
        int s4 = cs[p + 4], s5 = cs[p + 5], s6 = cs[p + 6], s7 = cs[p + 7];
        unsigned int u0 = mrow[(size_t)s0 * 64];
        unsigned int u1 = mrow[(size_t)s1 * 64];
        unsigned int u2 = mrow[(size_t)s2 * 64];
        unsigned int u3 = mrow[(size_t)s3 * 64];
        unsigned int u4 = mrow[(size_t)s4 * 64];
        unsigned int u5 = mrow[(size_t)s5 * 64];
        unsigned int u6 = mrow[(size_t)s6 * 64];
        unsigned int u7 = mrow[(size_t)s7 * 64];
        f32x2 a0 = __builtin_amdgcn_cvt_pk_f32_fp8(u0, false), b0 = __builtin_amdgcn_cvt_pk_f32_fp8(u0, true);
        f32x2 a1 = __builtin_amdgcn_cvt_pk_f32_fp8(u1, false), b1 = __builtin_amdgcn_cvt_pk_f32_fp8(u1, true);
        f32x2 a2 = __builtin_amdgcn_cvt_pk_f32_fp8(u2, false), b2 = __builtin_amdgcn_cvt_pk_f32_fp8(u2, true);
        f32x2 a3 = __builtin_amdgcn_cvt_pk_f32_fp8(u3, false), b3 = __builtin_amdgcn_cvt_pk_f32_fp8(u3, true);
        f32x2 a4 = __builtin_amdgcn_cvt_pk_f32_fp8(u4, false), b4 = __builtin_amdgcn_cvt_pk_f32_fp8(u4, true);
        f32x2 a5 = __builtin_amdgcn_cvt_pk_f32_fp8(u5, false), b5 = __builtin_amdgcn_cvt_pk_f32_fp8(u5, true);
        f32x2 a6 = __builtin_amdgcn_cvt_pk_f32_fp8(u6, false), b6 = __builtin_amdgcn_cvt_pk_f32_fp8(u6, true);
        f32x2 a7 = __builtin_amdgcn_cvt_pk_f32_fp8(u7, false), b7 = __builtin_amdgcn_cvt_pk_f32_fp8(u7, true);
        acc.x += ((a0.x + a1.x) + (a2.x + a3.x)) + ((a4.x + a5.x) + (a6.x + a7.x));
        acc.y += ((a0.y + a1.y) + (a2.y + a3.y)) + ((a4.y + a5.y) + (a6.y + a7.y));
        acc.z += ((b0.x + b1.x) + (b2.x + b3.x)) + ((b4.x + b5.x) + (b6.x + b7.x));
        acc.w += ((b0.y + b1.y) + (b2.y + b3.y)) + ((b4.y + b5.y) + (b6.y + b7.y));
    }
    for (; p < n; ++p) {
        int s = cs[p];
        unsigned int u = mrow[(size_t)s * 64];
        f32x2 a = __builtin_amdgcn_cvt_pk_f32_fp8(u, false);
        f32x2 b = __builtin_amdgcn_cvt_pk_f32_fp8(u, true);
        acc.x += a.x; acc.y += a.y; acc.z += b.x; acc.w += b.y;
    }
    float di = dinv[node];
    const float4 bb = *(const float4*)(bias + lane * 4);
    acc.x = acc.x * di + bb.x; acc.y = acc.y * di + bb.y;
    acc.z = acc.z * di + bb.z; acc.w = acc.w * di + bb.w;
    if (do_relu) {
        acc.x = fmaxf(acc.x, 0.f); acc.y = fmaxf(acc.y, 0.f);
        acc.z = fmaxf(acc.z, 0.f); acc.w = fmaxf(acc.w, 0.f);
    }
    outb[(size_t)node * 64 + lane] = pk4fp8(acc.x, acc.y, acc.z, acc.w);
}

// ---------------- pooling over fp8 h (mean over graphs) ----------------
__global__ __launch_bounds__(256) void k_pool(const unsigned int* __restrict__ h,  // [NN][64] dwords
                                              const int* __restrict__ batch,
                                              float* __restrict__ pooled, float* __restrict__ cnts) {
    __shared__ float pl[GG * 256];
    __shared__ float cl[GG];
    int t = threadIdx.x;
    for (int i = t; i < GG * 256; i += 256) pl[i] = 0.f;
    if (t < GG) cl[t] = 0.f;
    __syncthreads();
    int sub = t >> 6;
    int fd = t & 63;              // feature dword
    int chunk = (NN + gridDim.x - 1) / gridDim.x;
    int i0 = blockIdx.x * chunk;
    int i1 = i0 + chunk; if (i1 > NN) i1 = NN;
    int gcur = -1;
    float a0 = 0.f, a1 = 0.f, a2 = 0.f, a3 = 0.f, cr = 0.f;
    for (int i = i0 + sub; i < i1; i += 4) {
        int g = batch[i];
        if (g != gcur) {
            if (gcur >= 0) {
                atomicAdd(&pl[gcur * 256 + fd * 4 + 0], a0);
                atomicAdd(&pl[gcur * 256 + fd * 4 + 1], a1);
                atomicAdd(&pl[gcur * 256 + fd * 4 + 2], a2);
                atomicAdd(&pl[gcur * 256 + fd * 4 + 3], a3);
                if (fd == 0) atomicAdd(&cl[gcur], cr);
            }
            gcur = g; a0 = a1 = a2 = a3 = 0.f; cr = 0.f;
        }
        unsigned int u = h[(size_t)i * 64 + fd];
        f32x2 lo = __builtin_amdgcn_cvt_pk_f32_fp8(u, false);
        f32x2 hi = __builtin_amdgcn_cvt_pk_f32_fp8(u, true);
        a0 += lo.x; a1 += lo.y; a2 += hi.x; a3 += hi.y;
        cr += 1.f;
    }
    if (gcur >= 0) {
        atomicAdd(&pl[gcur * 256 + fd * 4 + 0], a0);
        atomicAdd(&pl[gcur * 256 + fd * 4 + 1], a1);
        atomicAdd(&pl[gcur * 256 + fd * 4 + 2], a2);
        atomicAdd(&pl[gcur * 256 + fd * 4 + 3], a3);
        if (fd == 0) atomicAdd(&cl[gcur], cr);
    }
    __syncthreads();
    for (int i = t; i < GG * 256; i += 256)
        if (pl[i] != 0.f) atomicAdd(&pooled[i], pl[i]);
    if (t < GG && cl[t] != 0.f) atomicAdd(&cnts[t], cl[t]);
}

// ---------------- head ----------------
__global__ __launch_bounds__(1024) void k_head(const float* __restrict__ pooled, const float* __restrict__ cnts,
                                               const float* __restrict__ Wf, const float* __restrict__ bf,
                                               const float* __restrict__ Wp, const float* __restrict__ bp,
                                               float* __restrict__ out) {
    __shared__ float z[GG][64];
    int t = threadIdx.x;
    int g = t >> 6, j = t & 63;
    float inv = 1.f / fmaxf(cnts[g], 1.f);
    float acc = 0.f;
    for (int k = 0; k < 256; ++k) acc += pooled[g * 256 + k] * Wf[k * 64 + j];
    z[g][j] = acc * inv + bf[j];
    __syncthreads();
    if (t < GG) {
        float o = 0.f;
        for (int j2 = 0; j2 < 64; ++j2) o += z[t][j2] * Wp[j2];
        o += bp[0];
        out[t] = 1.f / (1.f + expf(-o));
    }
}

extern "C" void kernel_launch(void* const* d_in, const int* in_sizes, int n_in,
                              void* d_out, int out_size, void* d_ws, size_t ws_size,
                              hipStream_t stream) {
    const float* x   = (const float*)d_in[0];
    const int*   ei  = (const int*)d_in[1];
    const int*   bat = (const int*)d_in[2];
    const float* W1  = (const float*)d_in[3];
    const float* b1  = (const float*)d_in[4];
    const float* W2  = (const float*)d_in[5];
    const float* b2  = (const float*)d_in[6];
    const float* W3  = (const float*)d_in[7];
    const float* b3  = (const float*)d_in[8];
    const float* Wf  = (const float*)d_in[9];
    const float* bf  = (const float*)d_in[10];
    const float* Wp  = (const float*)d_in[11];
    const float* bp  = (const float*)d_in[12];
    float* out = (float*)d_out;

    char* w = (char*)d_ws;
    unsigned char* xb  = (unsigned char*)w;  w += (size_t)NN * DD;         // fp8 x, 25.6 MB
    unsigned char* mb  = (unsigned char*)w;  w += (size_t)NN * HH;         // fp8 prescaled gemm out
    unsigned char* hb  = (unsigned char*)w;  w += (size_t)NCH * 25000 * 4; // 25.6 MB: histg (12.8 used), then fp8 h
    unsigned char* hb2 = (unsigned char*)w;  w += (size_t)NCH * 25000 * 4; // 25.6 MB: offg, then fp8 h
    unsigned char* W1t = (unsigned char*)w;  w += (size_t)DD * HH;
    unsigned char* W2t = (unsigned char*)w;  w += (size_t)HH * HH;
    unsigned char* W3t = (unsigned char*)w;  w += (size_t)HH * HH;
    float* dinv   = (float*)w;               w += (size_t)NN * 4;
    int*   cnt    = (int*)w;                 w += (size_t)NN * 4;
    unsigned short* bucket = (unsigned short*)w; w += (size_t)NN * BK * 2; // 9.6 MB
    float* pooled = (float*)w;               w += (size_t)GG * HH * 4;
    float* cnts   = (float*)w;               w += (size_t)GG * 4;
    unsigned int* gticket = (unsigned int*)w; w += 4;

    unsigned int* histg = (unsigned int*)hb;
    unsigned int* offg  = (unsigned int*)hb2;

    // zero pooled + cnts + gticket (contiguous)
    hipMemsetAsync(pooled, 0, (size_t)(GG * HH + GG + 1) * 4, stream);

    // cooperative build: hist+converts | grid.sync | scan | grid.sync | place
    {
        void* args[] = { (void*)&ei, (void*)&histg, (void*)&offg, (void*)&cnt, (void*)&dinv,
                         (void*)&bucket, (void*)&x, (void*)&xb,
                         (void*)&W1, (void*)&W2, (void*)&W3,
                         (void*)&W1t, (void*)&W2t, (void*)&W3t, (void*)&gticket };
        hipLaunchCooperativeKernel((void*)k_build, dim3(NBLD), dim3(256), args, 0, stream);
    }

    dim3 gg((NN + 127) / 128, 2);
    // layer 1
    k_gemm_fp8<<<gg, 256, 0, stream>>>(xb, W1t, dinv, mb, NN, DD);
    k_agg<<<(NN + 3) / 4, 256, 0, stream>>>((const unsigned int*)mb, b1, dinv, cnt, bucket,
                                            (unsigned int*)hb, 1);
    // layer 2
    k_gemm_fp8<<<gg, 256, 0, stream>>>(hb, W2t, dinv, mb, NN, HH);
    k_agg<<<(NN + 3) / 4, 256, 0, stream>>>((const unsigned int*)mb, b2, dinv, cnt, bucket,
                                            (unsigned int*)hb2, 1);
    // layer 3
    k_gemm_fp8<<<gg, 256, 0, stream>>>(hb2, W3t, dinv, mb, NN, HH);
    k_agg<<<(NN + 3) / 4, 256, 0, stream>>>((const unsigned int*)mb, b3, dinv, cnt, bucket,
                                            (unsigned int*)hb, 0);

    k_pool<<<256, 256, 0, stream>>>((const unsigned int*)hb, bat, pooled, cnts);
    k_head<<<1, 1024, 0, stream>>>(pooled, cnts, Wf, bf, Wp, bp, out);
}

// Round 4
// 518.523 us; speedup vs baseline: 1.5600x; 1.5600x over previous
//
#include <hip/hip_runtime.h>
#include <hip/hip_bf16.h>

#define NN 50000
#define EE 1600000
#define DD 512
#define HH 256
#define GG 16
#define BK 96     // bucket capacity (deg ~ Poisson(32), P(>=96) ~ 1e-18)
#define NCH 256   // edge chunks
#define CHSZ 6250 // EE / NCH

typedef long fp8x8;                                         // 8 fp8 bytes = 2 VGPRs
typedef __attribute__((ext_vector_type(4))) float f32x4;
typedef __attribute__((ext_vector_type(2))) float f32x2;

__device__ __forceinline__ unsigned char f2fp8(float f) {
    return (unsigned char)(__builtin_amdgcn_cvt_pk_fp8_f32(f, f, 0, false) & 0xff);
}
__device__ __forceinline__ unsigned int pk4fp8(float a, float b, float c, float d) {
    unsigned int r = __builtin_amdgcn_cvt_pk_fp8_f32(a, b, 0, false);
    return __builtin_amdgcn_cvt_pk_fp8_f32(c, d, r, true);
}

// ---------------- pass 1 (fused): per-chunk dst histograms + x->fp8 + W->fp8^T ----------------
// (round-2 proven version, 546us total) blocks [0,1024): histogram; [1024,7274): x convert;
// [7274,8298): weight transpose-convert.
__global__ __launch_bounds__(256) void k_hist_cvt(const int* __restrict__ ei,
                                                  unsigned int* __restrict__ histg,
                                                  const float* __restrict__ x, unsigned char* __restrict__ xb,
                                                  const float* __restrict__ W1, const float* __restrict__ W2,
                                                  const float* __restrict__ W3, unsigned char* __restrict__ W1t,
                                                  unsigned char* __restrict__ W2t, unsigned char* __restrict__ W3t) {
    __shared__ unsigned int hp[6250];
    int b = blockIdx.x, t = threadIdx.x;
    if (b < 1024) {
        int j = b >> 2, q = b & 3;
        int dlo = q * 12500;            // even -> parity(ld)==parity(d)
        for (int i = t; i < 6250; i += 256) hp[i] = 0;
        __syncthreads();
        int base = j * CHSZ;
        for (int k = 0; k < 25; ++k) {
            int o = k * 256 + t;
            if (o < CHSZ) {
                int d = ei[EE + base + o];
                unsigned int ld = (unsigned)(d - dlo);
                if (ld < 12500u) atomicAdd(&hp[ld >> 1], (ld & 1) ? 65536u : 1u);
            }
        }
        __syncthreads();
        unsigned int* dst = histg + j * 25000 + q * 6250;
        for (int i = t; i < 6250; i += 256) dst[i] = hp[i];
    } else if (b < 7274) {
        size_t i0 = ((size_t)(b - 1024) * 256 + t) * 16;   // 16 floats per thread
        float4 v0 = *(const float4*)(x + i0);
        float4 v1 = *(const float4*)(x + i0 + 4);
        float4 v2 = *(const float4*)(x + i0 + 8);
        float4 v3 = *(const float4*)(x + i0 + 12);
        uint4 o;
        o.x = pk4fp8(v0.x, v0.y, v0.z, v0.w);
        o.y = pk4fp8(v1.x, v1.y, v1.z, v1.w);
        o.z = pk4fp8(v2.x, v2.y, v2.z, v2.w);
        o.w = pk4fp8(v3.x, v3.y, v3.z, v3.w);
        *(uint4*)(xb + i0) = o;
    } else {
        int u = (b - 7274) * 256 + t;
        if (u < 131072) {
            int k = u >> 8, n = u & 255;
            W1t[(size_t)n * 512 + k] = f2fp8(W1[u]);
        } else if (u < 196608) {
            int q = u - 131072; int k = q >> 8, n = q & 255;
            W2t[(size_t)n * 256 + k] = f2fp8(W2[q]);
        } else {
            int q = u - 196608; int k = q >> 8, n = q & 255;
            W3t[(size_t)n * 256 + k] = f2fp8(W3[q]);
        }
    }
}

// ---------------- pass 2: parallel exclusive scan over chunks + cnt/dinv (round-2 version) ----------------
__global__ __launch_bounds__(256) void k_scan(const unsigned int* __restrict__ histg,
                                              unsigned int* __restrict__ offg,
                                              int* __restrict__ cnt, float* __restrict__ dinv) {
    __shared__ unsigned int part[8][32];
    int t = threadIdx.x;
    int il = t & 31, g = t >> 5;
    int i = blockIdx.x * 32 + il;
    bool ok = (i < 25000);
    unsigned int hv[32];
    unsigned int p0 = 0, p1 = 0;
    if (ok) {
        const unsigned int* hp = histg + (size_t)(g * 32) * 25000 + i;
        #pragma unroll
        for (int jj = 0; jj < 32; ++jj) hv[jj] = hp[(size_t)jj * 25000];
        #pragma unroll
        for (int jj = 0; jj < 32; ++jj) { p0 += hv[jj] & 0xffffu; p1 += hv[jj] >> 16; }
    }
    part[g][il] = p0 | (p1 << 16);
    __syncthreads();
    unsigned int b0 = 0, b1 = 0;
    #pragma unroll
    for (int g2 = 0; g2 < 7; ++g2) {
        if (g2 < g) { unsigned int p = part[g2][il]; b0 += p & 0xffffu; b1 += p >> 16; }
    }
    if (ok && g == 7) {
        unsigned int tot0 = b0 + p0, tot1 = b1 + p1;
        cnt[2 * i]     = (int)tot0;
        cnt[2 * i + 1] = (int)tot1;
        dinv[2 * i]     = rsqrtf((float)tot0 + 1.0f);
        dinv[2 * i + 1] = rsqrtf((float)tot1 + 1.0f);
    }
    if (ok) {
        unsigned int run0 = b0, run1 = b1;
        unsigned int* op = offg + (size_t)(g * 32) * 25000 + i;
        #pragma unroll
        for (int jj = 0; jj < 32; ++jj) {
            op[(size_t)jj * 25000] = run0 | (run1 << 16);
            run0 += hv[jj] & 0xffffu; run1 += hv[jj] >> 16;
        }
    }
}

// ---------------- pass 3: atomic-free placement, XCD-partitioned (round-2 version) ----------------
__global__ __launch_bounds__(256) void k_place(const int* __restrict__ ei,
                                               const unsigned int* __restrict__ offg,
                                               unsigned short* __restrict__ bucket) {
    __shared__ unsigned int cur[3125];
    int b = blockIdx.x, t = threadIdx.x;
    int x8 = b & 7, j = b >> 3;
    int lo = x8 * CHSZ;                 // lo even -> parity(ld)==parity(d)
    for (int i = t; i < 3125; i += 256) cur[i] = 0;
    __syncthreads();
    int base = j * CHSZ;
    for (int k = 0; k < 25; ++k) {
        int o = k * 256 + t;
        if (o < CHSZ) {
            int d = ei[EE + base + o];
            unsigned ld = (unsigned)(d - lo);
            if (ld < 6250u) {
                int s = ei[base + o];
                unsigned old = atomicAdd(&cur[ld >> 1], (ld & 1) ? 65536u : 1u);
                unsigned rank = (ld & 1) ? (old >> 16) : (old & 0xffffu);
                unsigned ov = offg[j * 25000 + (d >> 1)];
                unsigned pos = ((d & 1) ? (ov >> 16) : (ov & 0xffffu)) + rank;
                if (pos < BK) bucket[(size_t)d * BK + pos] = (unsigned short)s;
            }
        }
    }
}

// ---------------- fp8 MFMA GEMM: C = fp8(dinv[row] * (A @ Bt^T)) ----------------
// T3-lite 2-phase pipeline: double-buffered LDS, BK=64, stage(t+1) overlaps compute(t).
// LDS rows 64 B with 16-B XOR swizzle (slot = gchunk ^ (row&3)): applied on BOTH the
// global staging source and the ds_read address (linear gload_lds dest stays legal).
__global__ __launch_bounds__(256) void k_gemm_fp8(const unsigned char* __restrict__ A,
                                                  const unsigned char* __restrict__ Bt,
                                                  const float* __restrict__ dinv,
                                                  unsigned char* __restrict__ C, int M, int K) {
    __shared__ unsigned char As[2][8192];   // [buf][128 rows][64 B]
    __shared__ unsigned char Bs[2][8192];
    const int tid  = threadIdx.x;
    const int wave = tid >> 6;
    const int lane = tid & 63;
    const int row0 = blockIdx.x * 128;
    const int col0 = blockIdx.y * 128;
    const int wr = wave & 1;
    const int wc = wave >> 1;
    const int l15 = lane & 15;
    const int quad = lane >> 4;

    // staging geometry: thread (wave,lane) fills LDS bytes wave*1024 + lane*16
    // = row (wave*16 + lane/4), 16-B slot (lane&3). Source chunk = slot ^ (row&3).
    const int srow = (wave << 4) + (lane >> 2);
    const int gk16 = (((lane & 3) ^ (srow & 3)) << 4);
    int arow1 = row0 + srow;      if (arow1 >= M) arow1 = M - 1;
    int arow2 = row0 + srow + 64; if (arow2 >= M) arow2 = M - 1;
    const int brow1 = col0 + srow;
    const int brow2 = brow1 + 64;

#define STAGE(BUF, KB) do {                                                              \
    const unsigned char* ga1_ = A  + (size_t)arow1 * K + (KB) + gk16;                    \
    const unsigned char* ga2_ = A  + (size_t)arow2 * K + (KB) + gk16;                    \
    const unsigned char* gb1_ = Bt + (size_t)brow1 * K + (KB) + gk16;                    \
    const unsigned char* gb2_ = Bt + (size_t)brow2 * K + (KB) + gk16;                    \
    __builtin_amdgcn_global_load_lds((const __attribute__((address_space(1))) void*)ga1_,\
        (__attribute__((address_space(3))) void*)&As[BUF][wave * 1024], 16, 0, 0);       \
    __builtin_amdgcn_global_load_lds((const __attribute__((address_space(1))) void*)ga2_,\
        (__attribute__((address_space(3))) void*)&As[BUF][4096 + wave * 1024], 16, 0, 0);\
    __builtin_amdgcn_global_load_lds((const __attribute__((address_space(1))) void*)gb1_,\
        (__attribute__((address_space(3))) void*)&Bs[BUF][wave * 1024], 16, 0, 0);       \
    __builtin_amdgcn_global_load_lds((const __attribute__((address_space(1))) void*)gb2_,\
        (__attribute__((address_space(3))) void*)&Bs[BUF][4096 + wave * 1024], 16, 0, 0);\
} while (0)

    f32x4 acc[4][4];
    #pragma unroll
    for (int i = 0; i < 4; ++i)
        #pragma unroll
        for (int j = 0; j < 4; ++j)
            acc[i][j] = (f32x4){0.f, 0.f, 0.f, 0.f};

    const int NT = K >> 6;    // K=512 -> 8, K=256 -> 4
    STAGE(0, 0);
    __syncthreads();          // drains vmcnt: buf0 ready

    for (int t = 0; t < NT; ++t) {
        const int cb = t & 1;
        if (t + 1 < NT) STAGE(cb ^ 1, (t + 1) << 6);   // prefetch overlaps compute below

        fp8x8 af[2][4], bfr[2][4];
        #pragma unroll
        for (int kk = 0; kk < 2; ++kk) {
            const int csw = (((kk * 2 + (quad >> 1)) ^ (l15 & 3)) << 4) + ((quad & 1) << 3);
            #pragma unroll
            for (int mi = 0; mi < 4; ++mi) {
                af[kk][mi]  = *(const fp8x8*)&As[cb][(wr * 64 + mi * 16 + l15) * 64 + csw];
                bfr[kk][mi] = *(const fp8x8*)&Bs[cb][(wc * 64 + mi * 16 + l15) * 64 + csw];
            }
        }
        #pragma unroll
        for (int kk = 0; kk < 2; ++kk)
            #pragma unroll
            for (int mi = 0; mi < 4; ++mi)
                #pragma unroll
                for (int ni = 0; ni < 4; ++ni)
                    acc[mi][ni] = __builtin_amdgcn_mfma_f32_16x16x32_fp8_fp8(af[kk][mi], bfr[kk][ni], acc[mi][ni], 0, 0, 0);

        __syncthreads();      // drains vmcnt (next buf staged) + all waves done reading cb
    }
#undef STAGE

    #pragma unroll
    for (int mi = 0; mi < 4; ++mi) {
        #pragma unroll
        for (int r = 0; r < 4; ++r) {
            int grow = row0 + wr * 64 + mi * 16 + quad * 4 + r;
            if (grow < M) {
                float ds = dinv[grow];
                #pragma unroll
                for (int ni = 0; ni < 4; ++ni) {
                    int gcol = col0 + wc * 64 + ni * 16 + l15;
                    C[(size_t)grow * 256 + gcol] = f2fp8(ds * acc[mi][ni][r]);
                }
            }
        }
    }
}

// ---------------- aggregation over fp8 rows; fp8 h output ----------------
// 16-deep gather pipeline; bucket indices loaded as uint4 (16 B) instead of 8 scalar loads.
__global__ __launch_bounds__(256) void k_agg(const unsigned int* __restrict__ m,   // [NN][64] dwords
                                             const float* __restrict__ bias,
                                             const float* __restrict__ dinv, const int* __restrict__ cnt,
                                             const unsigned short* __restrict__ bucket,
                                             unsigned int* __restrict__ outb,      // [NN][64] dwords fp8
                                             int do_relu) {
    int lane = threadIdx.x & 63;
    int node = blockIdx.x * 4 + (threadIdx.x >> 6);
    if (node >= NN) return;
    const unsigned int* mrow = m + lane;
    unsigned int v = mrow[(size_t)node * 64];
    f32x2 lo = __builtin_amdgcn_cvt_pk_f32_fp8(v, false);
    f32x2 hi = __builtin_amdgcn_cvt_pk_f32_fp8(v, true);
    float4 acc = make_float4(lo.x, lo.y, hi.x, hi.y);
    int n = cnt[node]; if (n > BK) n = BK;
    const unsigned short* cs = bucket + (size_t)node * BK;
    int p = 0;
    for (; p + 16 <= n; p += 16) {
        uint4 iv0 = *(const uint4*)(cs + p);        // 8 u16 indices
        uint4 iv1 = *(const uint4*)(cs + p + 8);
        unsigned int u0 = mrow[(size_t)(iv0.x & 0xffffu) * 64];
        unsigned int u1 = mrow[(size_t)(iv0.x >> 16)    * 64];
        unsigned int u2 = mrow[(size_t)(iv0.y & 0xffffu) * 64];
        unsigned int u3 = mrow[(size_t)(iv0.y >> 16)    * 64];
        unsigned int u4 = mrow[(size_t)(iv0.z & 0xffffu) * 64];
        unsigned int u5 = mrow[(size_t)(iv0.z >> 16)    * 64];
        unsigned int u6 = mrow[(size_t)(iv0.w & 0xffffu) * 64];
        unsigned int u7 = mrow[(size_t)(iv0.w >> 16)    * 64];
        unsigned int u8 = mrow[(size_t)(iv1.x & 0xffffu) * 64];
        unsigned int u9 = mrow[(size_t)(iv1.x >> 16)    * 64];
        unsigned int ua = mrow[(size_t)(iv1.y & 0xffffu) * 64];
        unsigned int ub = mrow[(size_t)(iv1.y >> 16)    * 64];
        unsigned int uc = mrow[(size_t)(iv1.z & 0xffffu) * 64];
        unsigned int ud = mrow[(size_t)(iv1.z >> 16)    * 64];
        unsigned int ue = mrow[(size_t)(iv1.w & 0xffffu) * 64];
        unsigned int uf = mrow[(size_t)(iv1.w >> 16)    * 64];
        f32x2 a0 = __builtin_amdgcn_cvt_pk_f32_fp8(u0, false), b0 = __builtin_amdgcn_cvt_pk_f32_fp8(u0, true);
        f32x2 a1 = __builtin_amdgcn_cvt_pk_f32_fp8(u1, false), b1 = __builtin_amdgcn_cvt_pk_f32_fp8(u1, true);
        f32x2 a2 = __builtin_amdgcn_cvt_pk_f32_fp8(u2, false), b2 = __builtin_amdgcn_cvt_pk_f32_fp8(u2, true);
        f32x2 a3 = __builtin_amdgcn_cvt_pk_f32_fp8(u3, false), b3 = __builtin_amdgcn_cvt_pk_f32_fp8(u3, true);
        f32x2 a4 = __builtin_amdgcn_cvt_pk_f32_fp8(u4, false), b4 = __builtin_amdgcn_cvt_pk_f32_fp8(u4, true);
        f32x2 a5 = __builtin_amdgcn_cvt_pk_f32_fp8(u5, false), b5 = __builtin_amdgcn_cvt_pk_f32_fp8(u5, true);
        f32x2 a6 = __builtin_amdgcn_cvt_pk_f32_fp8(u6, false), b6 = __builtin_amdgcn_cvt_pk_f32_fp8(u6, true);
        f32x2 a7 = __builtin_amdgcn_cvt_pk_f32_fp8(u7, false), b7 = __builtin_amdgcn_cvt_pk_f32_fp8(u7, true);
        f32x2 a8 = __builtin_amdgcn_cvt_pk_f32_fp8(u8, false), b8 = __builtin_amdgcn_cvt_pk_f32_fp8(u8, true);
        f32x2 a9 = __builtin_amdgcn_cvt_pk_f32_fp8(u9, false), b9 = __builtin_amdgcn_cvt_pk_f32_fp8(u9, true);
        f32x2 aa = __builtin_amdgcn_cvt_pk_f32_fp8(ua, false), ba = __builtin_amdgcn_cvt_pk_f32_fp8(ua, true);
        f32x2 ab = __builtin_amdgcn_cvt_pk_f32_fp8(ub, false), bb2 = __builtin_amdgcn_cvt_pk_f32_fp8(ub, true);
        f32x2 ac = __builtin_amdgcn_cvt_pk_f32_fp8(uc, false), bc = __builtin_amdgcn_cvt_pk_f32_fp8(uc, true);
        f32x2 ad = __builtin_amdgcn_cvt_pk_f32_fp8(ud, false), bd = __builtin_amdgcn_cvt_pk_f32_fp8(ud, true);
        f32x2 ae = __builtin_amdgcn_cvt_pk_f32_fp8(ue, false), be = __builtin_amdgcn_cvt_pk_f32_fp8(ue, true);
        f32x2 af2 = __builtin_amdgcn_cvt_pk_f32_fp8(uf, false), bf2 = __builtin_amdgcn_cvt_pk_f32_fp8(uf, true);
        acc.x += (((a0.x + a1.x) + (a2.x + a3.x)) + ((a4.x + a5.x) + (a6.x + a7.x)))
               + (((a8.x + a9.x) + (aa.x + ab.x)) + ((ac.x + ad.x) + (ae.x + af2.x)));
        acc.y += (((a0.y + a1.y) + (a2.y + a3.y)) + ((a4.y + a5.y) + (a6.y + a7.y)))
               + (((a8.y + a9.y) + (aa.y + ab.y)) + ((ac.y + ad.y) + (ae.y + af2.y)));
        acc.z += (((b0.x + b1.x) + (b2.x + b3.x)) + ((b4.x + b5.x) + (b6.x + b7.x)))
               + (((b8.x + b9.x) + (ba.x + bb2.x)) + ((bc.x + bd.x) + (be.x + bf2.x)));
        acc.w += (((b0.y + b1.y) + (b2.y + b3.y)) + ((b4.y + b5.y) + (b6.y + b7.y)))
               + (((b8.y + b9.y) + (ba.y + bb2.y)) + ((bc.y + bd.y) + (be.y + bf2.y)));
    }
    for (; p + 8 <= n; p += 8) {
        uint4 iv0 = *(const uint4*)(cs + p);
        unsigned int u0 = mrow[(size_t)(iv0.x & 0xffffu) * 64];
        unsigned int u1 = mrow[(size_t)(iv0.x >> 16)    * 64];
        unsigned int u2 = mrow[(size_t)(iv0.y & 0xffffu) * 64];
        unsigned int u3 = mrow[(size_t)(iv0.y >> 16)    * 64];
        unsigned int u4 = mrow[(size_t)(iv0.z & 0xffffu) * 64];
        unsigned int u5 = mrow[(size_t)(iv0.z >> 16)    * 64];
        unsigned int u6 = mrow[(size_t)(iv0.w & 0xffffu) * 64];
        unsigned int u7 = mrow[(size_t)(iv0.w >> 16)    * 64];
        f32x2 a0 = __builtin_amdgcn_cvt_pk_f32_fp8(u0, false), b0 = __builtin_amdgcn_cvt_pk_f32_fp8(u0, true);
        f32x2 a1 = __builtin_amdgcn_cvt_pk_f32_fp8(u1, false), b1 = __builtin_amdgcn_cvt_pk_f32_fp8(u1, true);
        f32x2 a2 = __builtin_amdgcn_cvt_pk_f32_fp8(u2, false), b2 = __builtin_amdgcn_cvt_pk_f32_fp8(u2, true);
        f32x2 a3 = __builtin_amdgcn_cvt_pk_f32_fp8(u3, false), b3 = __builtin_amdgcn_cvt_pk_f32_fp8(u3, true);
        f32x2 a4 = __builtin_amdgcn_cvt_pk_f32_fp8(u4, false), b4 = __builtin_amdgcn_cvt_pk_f32_fp8(u4, true);
        f32x2 a5 = __builtin_amdgcn_cvt_pk_f32_fp8(u5, false), b5 = __builtin_amdgcn_cvt_pk_f32_fp8(u5, true);
        f32x2 a6 = __builtin_amdgcn_cvt_pk_f32_fp8(u6, false), b6 = __builtin_amdgcn_cvt_pk_f32_fp8(u6, true);
        f32x2 a7 = __builtin_amdgcn_cvt_pk_f32_fp8(u7, false), b7 = __builtin_amdgcn_cvt_pk_f32_fp8(u7, true);
        acc.x += ((a0.x + a1.x) + (a2.x + a3.x)) + ((a4.x + a5.x) + (a6.x + a7.x));
        acc.y += ((a0.y + a1.y) + (a2.y + a3.y)) + ((a4.y + a5.y) + (a6.y + a7.y));
        acc.z += ((b0.x + b1.x) + (b2.x + b3.x)) + ((b4.x + b5.x) + (b6.x + b7.x));
        acc.w += ((b0.y + b1.y) + (b2.y + b3.y)) + ((b4.y + b5.y) + (b6.y + b7.y));
    }
    for (; p < n; ++p) {
        int s = cs[p];
        unsigned int u = mrow[(size_t)s * 64];
        f32x2 a = __builtin_amdgcn_cvt_pk_f32_fp8(u, false);
        f32x2 b = __builtin_amdgcn_cvt_pk_f32_fp8(u, true);
        acc.x += a.x; acc.y += a.y; acc.z += b.x; acc.w += b.y;
    }
    float di = dinv[node];
    const float4 bb = *(const float4*)(bias + lane * 4);
    acc.x = acc.x * di + bb.x; acc.y = acc.y * di + bb.y;
    acc.z = acc.z * di + bb.z; acc.w = acc.w * di + bb.w;
    if (do_relu) {
        acc.x = fmaxf(acc.x, 0.f); acc.y = fmaxf(acc.y, 0.f);
        acc.z = fmaxf(acc.z, 0.f); acc.w = fmaxf(acc.w, 0.f);
    }
    outb[(size_t)node * 64 + lane] = pk4fp8(acc.x, acc.y, acc.z, acc.w);
}

// ---------------- pooling over fp8 h (mean over graphs) ----------------
__global__ __launch_bounds__(256) void k_pool(const unsigned int* __restrict__ h,  // [NN][64] dwords
                                              const int* __restrict__ batch,
                                              float* __restrict__ pooled, float* __restrict__ cnts) {
    __shared__ float pl[GG * 256];
    __shared__ float cl[GG];
    int t = threadIdx.x;
    for (int i = t; i < GG * 256; i += 256) pl[i] = 0.f;
    if (t < GG) cl[t] = 0.f;
    __syncthreads();
    int sub = t >> 6;
    int fd = t & 63;              // feature dword
    int chunk = (NN + gridDim.x - 1) / gridDim.x;
    int i0 = blockIdx.x * chunk;
    int i1 = i0 + chunk; if (i1 > NN) i1 = NN;
    int gcur = -1;
    float a0 = 0.f, a1 = 0.f, a2 = 0.f, a3 = 0.f, cr = 0.f;
    for (int i = i0 + sub; i < i1; i += 4) {
        int g = batch[i];
        if (g != gcur) {
            if (gcur >= 0) {
                atomicAdd(&pl[gcur * 256 + fd * 4 + 0], a0);
                atomicAdd(&pl[gcur * 256 + fd * 4 + 1], a1);
                atomicAdd(&pl[gcur * 256 + fd * 4 + 2], a2);
                atomicAdd(&pl[gcur * 256 + fd * 4 + 3], a3);
                if (fd == 0) atomicAdd(&cl[gcur], cr);
            }
            gcur = g; a0 = a1 = a2 = a3 = 0.f; cr = 0.f;
        }
        unsigned int u = h[(size_t)i * 64 + fd];
        f32x2 lo = __builtin_amdgcn_cvt_pk_f32_fp8(u, false);
        f32x2 hi = __builtin_amdgcn_cvt_pk_f32_fp8(u, true);
        a0 += lo.x; a1 += lo.y; a2 += hi.x; a3 += hi.y;
        cr += 1.f;
    }
    if (gcur >= 0) {
        atomicAdd(&pl[gcur * 256 + fd * 4 + 0], a0);
        atomicAdd(&pl[gcur * 256 + fd * 4 + 1], a1);
        atomicAdd(&pl[gcur * 256 + fd * 4 + 2], a2);
        atomicAdd(&pl[gcur * 256 + fd * 4 + 3], a3);
        if (fd == 0) atomicAdd(&cl[gcur], cr);
    }
    __syncthreads();
    for (int i = t; i < GG * 256; i += 256)
        if (pl[i] != 0.f) atomicAdd(&pooled[i], pl[i]);
    if (t < GG && cl[t] != 0.f) atomicAdd(&cnts[t], cl[t]);
}

// ---------------- head ----------------
__global__ __launch_bounds__(1024) void k_head(const float* __restrict__ pooled, const float* __restrict__ cnts,
                                               const float* __restrict__ Wf, const float* __restrict__ bf,
                                               const float* __restrict__ Wp, const float* __restrict__ bp,
                                               float* __restrict__ out) {
    __shared__ float z[GG][64];
    int t = threadIdx.x;
    int g = t >> 6, j = t & 63;
    float inv = 1.f / fmaxf(cnts[g], 1.f);
    float acc = 0.f;
    for (int k = 0; k < 256; ++k) acc += pooled[g * 256 + k] * Wf[k * 64 + j];
    z[g][j] = acc * inv + bf[j];
    __syncthreads();
    if (t < GG) {
        float o = 0.f;
        for (int j2 = 0; j2 < 64; ++j2) o += z[t][j2] * Wp[j2];
        o += bp[0];
        out[t] = 1.f / (1.f + expf(-o));
    }
}

extern "C" void kernel_launch(void* const* d_in, const int* in_sizes, int n_in,
                              void* d_out, int out_size, void* d_ws, size_t ws_size,
                              hipStream_t stream) {
    const float* x   = (const float*)d_in[0];
    const int*   ei  = (const int*)d_in[1];
    const int*   bat = (const int*)d_in[2];
    const float* W1  = (const float*)d_in[3];
    const float* b1  = (const float*)d_in[4];
    const float* W2  = (const float*)d_in[5];
    const float* b2  = (const float*)d_in[6];
    const float* W3  = (const float*)d_in[7];
    const float* b3  = (const float*)d_in[8];
    const float* Wf  = (const float*)d_in[9];
    const float* bf  = (const float*)d_in[10];
    const float* Wp  = (const float*)d_in[11];
    const float* bp  = (const float*)d_in[12];
    float* out = (float*)d_out;

    char* w = (char*)d_ws;
    unsigned char* xb  = (unsigned char*)w;  w += (size_t)NN * DD;         // fp8 x, 25.6 MB
    unsigned char* mb  = (unsigned char*)w;  w += (size_t)NN * HH;         // fp8 prescaled gemm out
    unsigned char* hb  = (unsigned char*)w;  w += (size_t)NCH * 25000 * 4; // 25.6 MB: histg, then fp8 h
    unsigned char* hb2 = (unsigned char*)w;  w += (size_t)NCH * 25000 * 4; // 25.6 MB: offg, then fp8 h
    unsigned char* W1t = (unsigned char*)w;  w += (size_t)DD * HH;
    unsigned char* W2t = (unsigned char*)w;  w += (size_t)HH * HH;
    unsigned char* W3t = (unsigned char*)w;  w += (size_t)HH * HH;
    float* dinv   = (float*)w;               w += (size_t)NN * 4;
    int*   cnt    = (int*)w;                 w += (size_t)NN * 4;
    unsigned short* bucket = (unsigned short*)w; w += (size_t)NN * BK * 2; // 9.6 MB
    float* pooled = (float*)w;               w += (size_t)GG * HH * 4;
    float* cnts   = (float*)w;               w += (size_t)GG * 4;

    unsigned int* histg = (unsigned int*)hb;
    unsigned int* offg  = (unsigned int*)hb2;

    hipMemsetAsync(pooled, 0, (size_t)(GG * HH + GG) * 4, stream);

    // round-2 proven build: fused hist+converts, parallel scan, XCD-partitioned place
    k_hist_cvt<<<8298, 256, 0, stream>>>(ei, histg, x, xb, W1, W2, W3, W1t, W2t, W3t);
    k_scan<<<782, 256, 0, stream>>>(histg, offg, cnt, dinv);
    k_place<<<2048, 256, 0, stream>>>(ei, offg, bucket);

    dim3 gg((NN + 127) / 128, 2);
    // layer 1
    k_gemm_fp8<<<gg, 256, 0, stream>>>(xb, W1t, dinv, mb, NN, DD);
    k_agg<<<(NN + 3) / 4, 256, 0, stream>>>((const unsigned int*)mb, b1, dinv, cnt, bucket,
                                            (unsigned int*)hb, 1);
    // layer 2
    k_gemm_fp8<<<gg, 256, 0, stream>>>(hb, W2t, dinv, mb, NN, HH);
    k_agg<<<(NN + 3) / 4, 256, 0, stream>>>((const unsigned int*)mb, b2, dinv, cnt, bucket,
                                            (unsigned int*)hb2, 1);
    // layer 3
    k_gemm_fp8<<<gg, 256, 0, stream>>>(hb2, W3t, dinv, mb, NN, HH);
    k_agg<<<(NN + 3) / 4, 256, 0, stream>>>((const unsigned int*)mb, b3, dinv, cnt, bucket,
                                            (unsigned int*)hb, 0);

    k_pool<<<256, 256, 0, stream>>>((const unsigned int*)hb, bat, pooled, cnts);
    k_head<<<1, 1024, 0, stream>>>(pooled, cnts, Wf, bf, Wp, bp, out);
}